// Round 1
// baseline (723.412 us; speedup 1.0000x reference)
//
#include <hip/hip_runtime.h>

// LinearAttention: q=softmax(x@Wq^T+b); per fn: k=softmax(f@Wk^T+b), v=f@Wv^T+b,
// kv=k^T v, ksum=sum_l k, alpha=1/(q.ksum), out=alpha*q@kv; res=q+mean(out0,out1);
// final = res@Wo^T+bo.  B=4 L=8192 E=512 H=8 D=64.
//
// Round-0 plan: bf16 MFMA for the 6 big GEMMs (softmax fused in epilogue),
// VALU for the small kv/ksum reductions and the combine pass.

#define DEVI __device__ __forceinline__

using bf16x8 = __attribute__((ext_vector_type(8))) __bf16;
using f32x4  = __attribute__((ext_vector_type(4))) float;

static constexpr int LSEQ = 8192;
static constexpr int EDIM = 512;

DEVI unsigned short f2bf(float f) {  // RNE f32->bf16
  unsigned int u = __builtin_bit_cast(unsigned int, f);
  u += 0x7FFFu + ((u >> 16) & 1u);
  return (unsigned short)(u >> 16);
}
DEVI float bf2f(unsigned short s) {
  unsigned int u = ((unsigned int)s) << 16;
  return __builtin_bit_cast(float, u);
}

// ---------------- weight cast: 6 x [512x512] f32 -> bf16 ----------------
__global__ __launch_bounds__(256) void cast_w_k(
    const float* __restrict__ W0, const float* __restrict__ W1,
    const float* __restrict__ W2, const float* __restrict__ W3,
    const float* __restrict__ W4, const float* __restrict__ W5,
    unsigned short* __restrict__ dst) {
  const int m = blockIdx.y;
  const float* src = (m == 0) ? W0 : (m == 1) ? W1 : (m == 2) ? W2
                   : (m == 3) ? W3 : (m == 4) ? W4 : W5;
  const int idx = (blockIdx.x * 256 + threadIdx.x) * 8;
  const float4 a = *(const float4*)(src + idx);
  const float4 b = *(const float4*)(src + idx + 4);
  union { unsigned short u[8]; uint4 v; } p;
  p.u[0] = f2bf(a.x); p.u[1] = f2bf(a.y); p.u[2] = f2bf(a.z); p.u[3] = f2bf(a.w);
  p.u[4] = f2bf(b.x); p.u[5] = f2bf(b.y); p.u[6] = f2bf(b.z); p.u[7] = f2bf(b.w);
  *(uint4*)(dst + (size_t)m * 262144 + idx) = p.v;
}

// ---------------- GEMM: C[M,512] = A[M,512] @ W[512,512]^T + bias ----------------
// EPI: 0 = per-head softmax -> bf16 out; 1 = bias only -> bf16 out; 2 = bias only -> f32 out
// ABF: A operand is bf16 (true) or f32 (false, converted during LDS staging)
// Tile 128x128, 4 waves, BK=32, mfma_f32_16x16x32_bf16.
template <int EPI, bool ABF>
__global__ __launch_bounds__(256) void gemm_k(
    const void* __restrict__ Ap, const unsigned short* __restrict__ Wb,
    const float* __restrict__ bias, void* __restrict__ outp) {
  __shared__ unsigned short sA[128][40];
  __shared__ unsigned short sB[128][40];
  const int t = threadIdx.x;
  const int mtile = blockIdx.x, ntile = blockIdx.y;
  const int srow = t >> 1;
  const int c0 = (t & 1) * 16;
  const int w = t >> 6, lane = t & 63;
  const int wr = w >> 1, wc = w & 1, lg = lane >> 4, lr = lane & 15;

  const size_t aRow = (size_t)(mtile * 128 + srow) * EDIM;
  const size_t bRow = (size_t)(ntile * 128 + srow) * EDIM;
  const float* Af = (const float*)Ap;
  const unsigned short* Ab = (const unsigned short*)Ap;

  f32x4 acc[4][4];
#pragma unroll
  for (int i = 0; i < 4; ++i)
#pragma unroll
    for (int j = 0; j < 4; ++j)
#pragma unroll
      for (int c = 0; c < 4; ++c) acc[i][j][c] = 0.f;

  float bv[4];
#pragma unroll
  for (int fc = 0; fc < 4; ++fc) bv[fc] = bias[ntile * 128 + wc * 64 + fc * 16 + lr];

  for (int kt = 0; kt < 16; ++kt) {
    const int kk = kt * 32;
    if (ABF) {
      *(uint4*)&sA[srow][c0]     = *(const uint4*)(Ab + aRow + kk + c0);
      *(uint4*)&sA[srow][c0 + 8] = *(const uint4*)(Ab + aRow + kk + c0 + 8);
    } else {
      const float4 a0 = *(const float4*)(Af + aRow + kk + c0);
      const float4 a1 = *(const float4*)(Af + aRow + kk + c0 + 4);
      const float4 a2 = *(const float4*)(Af + aRow + kk + c0 + 8);
      const float4 a3 = *(const float4*)(Af + aRow + kk + c0 + 12);
      union { unsigned short u[8]; uint4 v; } p0, p1;
      p0.u[0] = f2bf(a0.x); p0.u[1] = f2bf(a0.y); p0.u[2] = f2bf(a0.z); p0.u[3] = f2bf(a0.w);
      p0.u[4] = f2bf(a1.x); p0.u[5] = f2bf(a1.y); p0.u[6] = f2bf(a1.z); p0.u[7] = f2bf(a1.w);
      p1.u[0] = f2bf(a2.x); p1.u[1] = f2bf(a2.y); p1.u[2] = f2bf(a2.z); p1.u[3] = f2bf(a2.w);
      p1.u[4] = f2bf(a3.x); p1.u[5] = f2bf(a3.y); p1.u[6] = f2bf(a3.z); p1.u[7] = f2bf(a3.w);
      *(uint4*)&sA[srow][c0]     = p0.v;
      *(uint4*)&sA[srow][c0 + 8] = p1.v;
    }
    *(uint4*)&sB[srow][c0]     = *(const uint4*)(Wb + bRow + kk + c0);
    *(uint4*)&sB[srow][c0 + 8] = *(const uint4*)(Wb + bRow + kk + c0 + 8);
    __syncthreads();
    bf16x8 af[4], bfr[4];
#pragma unroll
    for (int fr = 0; fr < 4; ++fr)
      af[fr] = *(const bf16x8*)&sA[wr * 64 + fr * 16 + lr][lg * 8];
#pragma unroll
    for (int fc = 0; fc < 4; ++fc)
      bfr[fc] = *(const bf16x8*)&sB[wc * 64 + fc * 16 + lr][lg * 8];
#pragma unroll
    for (int fr = 0; fr < 4; ++fr)
#pragma unroll
      for (int fc = 0; fc < 4; ++fc)
        acc[fr][fc] = __builtin_amdgcn_mfma_f32_16x16x32_bf16(af[fr], bfr[fc], acc[fr][fc], 0, 0, 0);
    __syncthreads();
  }

  // epilogue: C/D map col=lane&15, row=(lane>>4)*4+reg  [verified m89/m91]
  const int cb = ntile * 128 + wc * 64;
  const int rb = mtile * 128 + wr * 64;
#pragma unroll
  for (int fr = 0; fr < 4; ++fr) {
#pragma unroll
    for (int j = 0; j < 4; ++j) {
      float v0 = acc[fr][0][j] + bv[0];
      float v1 = acc[fr][1][j] + bv[1];
      float v2 = acc[fr][2][j] + bv[2];
      float v3 = acc[fr][3][j] + bv[3];
      if (EPI == 0) {
        // row-softmax over this wave's 64 cols (= one head): reduce over fc + 16 lanes
        float mx = fmaxf(fmaxf(v0, v1), fmaxf(v2, v3));
#pragma unroll
        for (int mk = 1; mk < 16; mk <<= 1) mx = fmaxf(mx, __shfl_xor(mx, mk, 64));
        v0 = __expf(v0 - mx); v1 = __expf(v1 - mx);
        v2 = __expf(v2 - mx); v3 = __expf(v3 - mx);
        float s = v0 + v1 + v2 + v3;
#pragma unroll
        for (int mk = 1; mk < 16; mk <<= 1) s += __shfl_xor(s, mk, 64);
        const float inv = 1.f / s;
        v0 *= inv; v1 *= inv; v2 *= inv; v3 *= inv;
      }
      const size_t row = (size_t)(rb + fr * 16 + lg * 4 + j);
      if (EPI == 2) {
        float* o = (float*)outp;
        o[row * EDIM + cb +  0 + lr] = v0;
        o[row * EDIM + cb + 16 + lr] = v1;
        o[row * EDIM + cb + 32 + lr] = v2;
        o[row * EDIM + cb + 48 + lr] = v3;
      } else {
        unsigned short* o = (unsigned short*)outp;
        o[row * EDIM + cb +  0 + lr] = f2bf(v0);
        o[row * EDIM + cb + 16 + lr] = f2bf(v1);
        o[row * EDIM + cb + 32 + lr] = f2bf(v2);
        o[row * EDIM + cb + 48 + lr] = f2bf(v3);
      }
    }
  }
}

// ---------------- kv = k^T v (64x64 per b,h) + ksum, via LDS tiles + atomics ----------------
// grid (16 L-chunks of 512, 32 bh); block 256 = 16x16 threads, 4x4 outputs each.
__global__ __launch_bounds__(256) void reduce_kv_k(
    const unsigned short* __restrict__ Kb, const unsigned short* __restrict__ Vb,
    float* __restrict__ KV, float* __restrict__ KS) {
  __shared__ unsigned short sK[64][80];
  __shared__ unsigned short sV[64][80];
  const int t = threadIdx.x;
  const int bh = blockIdx.y;
  const int b = bh >> 3, h = bh & 7;
  const int ty = t >> 4, tx = t & 15;
  const int srow = t >> 2, scol = (t & 3) * 16;
  const size_t base = ((size_t)b * LSEQ + (size_t)blockIdx.x * 512) * EDIM + h * 64;
  float acc[4][4];
#pragma unroll
  for (int i = 0; i < 4; ++i)
#pragma unroll
    for (int j = 0; j < 4; ++j) acc[i][j] = 0.f;
  float ks[4] = {0.f, 0.f, 0.f, 0.f};

  for (int sub = 0; sub < 8; ++sub) {
    const size_t g = base + (size_t)(sub * 64 + srow) * EDIM + scol;
    *(uint4*)&sK[srow][scol]     = *(const uint4*)(Kb + g);
    *(uint4*)&sK[srow][scol + 8] = *(const uint4*)(Kb + g + 8);
    *(uint4*)&sV[srow][scol]     = *(const uint4*)(Vb + g);
    *(uint4*)&sV[srow][scol + 8] = *(const uint4*)(Vb + g + 8);
    __syncthreads();
#pragma unroll 4
    for (int l = 0; l < 64; ++l) {
      const ushort4 ku = *(const ushort4*)&sK[l][ty * 4];
      const ushort4 vu = *(const ushort4*)&sV[l][tx * 4];
      const float kf[4] = {bf2f(ku.x), bf2f(ku.y), bf2f(ku.z), bf2f(ku.w)};
      const float vf[4] = {bf2f(vu.x), bf2f(vu.y), bf2f(vu.z), bf2f(vu.w)};
#pragma unroll
      for (int i = 0; i < 4; ++i)
#pragma unroll
        for (int j = 0; j < 4; ++j) acc[i][j] = fmaf(kf[i], vf[j], acc[i][j]);
      if (tx == 0) {
#pragma unroll
        for (int i = 0; i < 4; ++i) ks[i] += kf[i];
      }
    }
    __syncthreads();
  }
  float* kvd = KV + (size_t)bh * 4096;
#pragma unroll
  for (int i = 0; i < 4; ++i)
#pragma unroll
    for (int j = 0; j < 4; ++j)
      atomicAdd(&kvd[(ty * 4 + i) * 64 + tx * 4 + j], acc[i][j]);
  if (tx == 0) {
#pragma unroll
    for (int i = 0; i < 4; ++i) atomicAdd(&KS[bh * 64 + ty * 4 + i], ks[i]);
  }
}

// ---------------- res = q + 0.5*(a0*q@kv0 + a1*q@kv1), a=1/(q.ksum) ----------------
// one wave per (row, head): lane = d/e index; kv columns live in registers.
__global__ __launch_bounds__(256) void combine_k(
    const unsigned short* __restrict__ Qb,
    const float* __restrict__ KV0, const float* __restrict__ KV1,
    const float* __restrict__ KS0, const float* __restrict__ KS1,
    unsigned short* __restrict__ Res) {
  const int t = threadIdx.x;
  const int bh = blockIdx.y, b = bh >> 3, h = bh & 7;
  const int w = t >> 6, lane = t & 63;
  const float* kv0 = KV0 + (size_t)bh * 4096;
  const float* kv1 = KV1 + (size_t)bh * 4096;
  float r0[64], r1[64];
#pragma unroll
  for (int d = 0; d < 64; ++d) {
    r0[d] = kv0[d * 64 + lane];
    r1[d] = kv1[d * 64 + lane];
  }
  const float ks0v = KS0[bh * 64 + lane];
  const float ks1v = KS1[bh * 64 + lane];
  const int rbase = blockIdx.x * 256 + w * 64;
  for (int i = 0; i < 64; ++i) {
    const int l = rbase + i;
    const size_t g = ((size_t)b * LSEQ + l) * EDIM + h * 64 + lane;
    const float qv = bf2f(Qb[g]);
    float a0 = qv * ks0v, a1 = qv * ks1v;
#pragma unroll
    for (int mk = 1; mk < 64; mk <<= 1) {
      a0 += __shfl_xor(a0, mk, 64);
      a1 += __shfl_xor(a1, mk, 64);
    }
    const float al0 = 1.f / a0, al1 = 1.f / a1;
    float o0 = 0.f, o1 = 0.f;
#pragma unroll
    for (int d = 0; d < 64; ++d) {
      const float qd = __builtin_bit_cast(float,
          __builtin_amdgcn_readlane(__builtin_bit_cast(int, qv), d));
      o0 = fmaf(qd, r0[d], o0);
      o1 = fmaf(qd, r1[d], o1);
    }
    const float res = qv + 0.5f * (al0 * o0 + al1 * o1);
    Res[g] = f2bf(res);
  }
}

extern "C" void kernel_launch(void* const* d_in, const int* in_sizes, int n_in,
                              void* d_out, int out_size, void* d_ws, size_t ws_size,
                              hipStream_t stream) {
  const float* query = (const float*)d_in[0];
  const float* f0    = (const float*)d_in[1];
  const float* f1    = (const float*)d_in[2];
  const float* Wq  = (const float*)d_in[3];  const float* bq  = (const float*)d_in[4];
  const float* Wk0 = (const float*)d_in[5];  const float* bk0 = (const float*)d_in[6];
  const float* Wv0 = (const float*)d_in[7];  const float* bv0 = (const float*)d_in[8];
  const float* Wk1 = (const float*)d_in[9];  const float* bk1 = (const float*)d_in[10];
  const float* Wv1 = (const float*)d_in[11]; const float* bv1 = (const float*)d_in[12];
  const float* Wo  = (const float*)d_in[13]; const float* bo  = (const float*)d_in[14];
  char* ws = (char*)d_ws;

  // ws layout (bytes): [0,3M) bf16 weights x6; [4M,5M+16K) kv0,kv1,ks0,ks1 (f32, zeroed);
  // [8M,40M) Q bf16; [40M,72M) K bf16 (reused as RES); [72M,104M) V bf16.
  unsigned short* WB = (unsigned short*)ws;
  float* KV0 = (float*)(ws + (4ull << 20));
  float* KV1 = (float*)(ws + (4ull << 20) + (512ull << 10));
  float* KS0 = (float*)(ws + (5ull << 20));
  float* KS1 = (float*)(ws + (5ull << 20) + (8ull << 10));
  unsigned short* Qb = (unsigned short*)(ws + (8ull << 20));
  unsigned short* Kb = (unsigned short*)(ws + (40ull << 20));
  unsigned short* Vb = (unsigned short*)(ws + (72ull << 20));
  unsigned short* Resb = Kb;  // K buffer is dead by the time combine writes
  float* outp = (float*)d_out;

  hipMemsetAsync(ws + (4ull << 20), 0, (1ull << 20) + (16ull << 10), stream);
  cast_w_k<<<dim3(128, 6), dim3(256), 0, stream>>>(Wq, Wk0, Wv0, Wk1, Wv1, Wo, WB);

  const dim3 gg(256, 4), gb(256);
  gemm_k<0, false><<<gg, gb, 0, stream>>>(query, WB + 0 * 262144, bq, Qb);   // q = softmax
  gemm_k<0, false><<<gg, gb, 0, stream>>>(f0,    WB + 1 * 262144, bk0, Kb);  // k0 = softmax
  gemm_k<1, false><<<gg, gb, 0, stream>>>(f0,    WB + 2 * 262144, bv0, Vb);  // v0
  reduce_kv_k<<<dim3(16, 32), gb, 0, stream>>>(Kb, Vb, KV0, KS0);
  gemm_k<0, false><<<gg, gb, 0, stream>>>(f1,    WB + 3 * 262144, bk1, Kb);  // k1
  gemm_k<1, false><<<gg, gb, 0, stream>>>(f1,    WB + 4 * 262144, bv1, Vb);  // v1
  reduce_kv_k<<<dim3(16, 32), gb, 0, stream>>>(Kb, Vb, KV1, KS1);
  combine_k<<<dim3(32, 32), gb, 0, stream>>>(Qb, KV0, KV1, KS0, KS1, Resb);
  gemm_k<2, true><<<gg, gb, 0, stream>>>(Resb, WB + 5 * 262144, bo, outp);   // final

  (void)in_sizes; (void)n_in; (void)out_size; (void)ws_size;
}

// Round 2
// 610.495 us; speedup vs baseline: 1.1850x; 1.1850x over previous
//
#include <hip/hip_runtime.h>

// LinearAttention B=4 L=8192 E=512 H=8 D=64.
// R2: all-bf16 MFMA GEMMs with global_load_lds (m97 structure), MFMA combine
// (kv stored transposed), VALU kv-reduce kept.

#define DEVI __device__ __forceinline__

using bf16x8 = __attribute__((ext_vector_type(8))) __bf16;
using f32x4  = __attribute__((ext_vector_type(4))) float;

static constexpr int LSEQ = 8192;
static constexpr int EDIM = 512;

DEVI unsigned short f2bf(float f) {  // RNE f32->bf16
  unsigned int u = __builtin_bit_cast(unsigned int, f);
  u += 0x7FFFu + ((u >> 16) & 1u);
  return (unsigned short)(u >> 16);
}
DEVI float bf2f(unsigned short s) {
  unsigned int u = ((unsigned int)s) << 16;
  return __builtin_bit_cast(float, u);
}

DEVI void glds16(const void* g, void* l) {
  __builtin_amdgcn_global_load_lds(
      (const __attribute__((address_space(1))) void*)g,
      (__attribute__((address_space(3))) void*)l, 16, 0, 0);
}

// ---------------- weight cast: 6 x [512x512] f32 -> bf16 ----------------
__global__ __launch_bounds__(256) void cast_w_k(
    const float* __restrict__ W0, const float* __restrict__ W1,
    const float* __restrict__ W2, const float* __restrict__ W3,
    const float* __restrict__ W4, const float* __restrict__ W5,
    unsigned short* __restrict__ dst) {
  const int m = blockIdx.y;
  const float* src = (m == 0) ? W0 : (m == 1) ? W1 : (m == 2) ? W2
                   : (m == 3) ? W3 : (m == 4) ? W4 : W5;
  const int idx = (blockIdx.x * 256 + threadIdx.x) * 8;
  const float4 a = *(const float4*)(src + idx);
  const float4 b = *(const float4*)(src + idx + 4);
  union { unsigned short u[8]; uint4 v; } p;
  p.u[0] = f2bf(a.x); p.u[1] = f2bf(a.y); p.u[2] = f2bf(a.z); p.u[3] = f2bf(a.w);
  p.u[4] = f2bf(b.x); p.u[5] = f2bf(b.y); p.u[6] = f2bf(b.z); p.u[7] = f2bf(b.w);
  *(uint4*)(dst + (size_t)m * 262144 + idx) = p.v;
}

// ---------------- input cast: [32768x512] f32 -> bf16 ----------------
__global__ __launch_bounds__(256) void cast_in_k(
    const float* __restrict__ src, unsigned short* __restrict__ dst) {
  const size_t idx = ((size_t)blockIdx.x * 256 + threadIdx.x) * 8;
  const float4 a = *(const float4*)(src + idx);
  const float4 b = *(const float4*)(src + idx + 4);
  union { unsigned short u[8]; uint4 v; } p;
  p.u[0] = f2bf(a.x); p.u[1] = f2bf(a.y); p.u[2] = f2bf(a.z); p.u[3] = f2bf(a.w);
  p.u[4] = f2bf(b.x); p.u[5] = f2bf(b.y); p.u[6] = f2bf(b.z); p.u[7] = f2bf(b.w);
  *(uint4*)(dst + idx) = p.v;
}

// ---------------- GEMM: C[M,512] = A[M,512](bf16) @ W[512,512]^T + bias ----------------
// EPI: 0 = per-head softmax -> bf16; 1 = bias -> bf16; 2 = bias -> f32
// m97 structure: 128x128 tile, BK=32, linear LDS, global_load_lds width 16.
template <int EPI>
__global__ __launch_bounds__(256) void gemm2_k(
    const unsigned short* __restrict__ Ab, const unsigned short* __restrict__ Wb,
    const float* __restrict__ bias, void* __restrict__ outp) {
  __shared__ unsigned short sA[4096];
  __shared__ unsigned short sB[4096];
  const int t = threadIdx.x;
  const int mtile = blockIdx.x, ntile = blockIdx.y;
  const int w = t >> 6, lane = t & 63, lg = lane >> 4, lr = lane & 15;
  const int wr = w >> 1, wc = w & 1;
  const int srow = t >> 2, scol = (t & 3) * 8;
  const unsigned short* gA = Ab + (size_t)(mtile * 128 + srow) * EDIM + scol;
  const unsigned short* gB = Wb + (size_t)(ntile * 128 + srow) * EDIM + scol;
  unsigned short* lA = sA + t * 8;
  unsigned short* lB = sB + t * 8;

  f32x4 acc[4][4];
#pragma unroll
  for (int i = 0; i < 4; ++i)
#pragma unroll
    for (int j = 0; j < 4; ++j)
#pragma unroll
      for (int c = 0; c < 4; ++c) acc[i][j][c] = 0.f;

  float bv[4];
#pragma unroll
  for (int fc = 0; fc < 4; ++fc) bv[fc] = bias[ntile * 128 + wc * 64 + fc * 16 + lr];

  for (int kt = 0; kt < 16; ++kt) {
    const int kk = kt * 32;
    glds16(gA + kk, lA);
    glds16(gA + 64 * EDIM + kk, lA + 2048);
    glds16(gB + kk, lB);
    glds16(gB + 64 * EDIM + kk, lB + 2048);
    __syncthreads();
    bf16x8 af[4], bfr[4];
#pragma unroll
    for (int fr = 0; fr < 4; ++fr)
      af[fr] = *(const bf16x8*)&sA[(wr * 64 + fr * 16 + lr) * 32 + lg * 8];
#pragma unroll
    for (int fc = 0; fc < 4; ++fc)
      bfr[fc] = *(const bf16x8*)&sB[(wc * 64 + fc * 16 + lr) * 32 + lg * 8];
#pragma unroll
    for (int fr = 0; fr < 4; ++fr)
#pragma unroll
      for (int fc = 0; fc < 4; ++fc)
        acc[fr][fc] = __builtin_amdgcn_mfma_f32_16x16x32_bf16(af[fr], bfr[fc], acc[fr][fc], 0, 0, 0);
    __syncthreads();
  }

  // epilogue: C/D map col=lane&15, row=(lane>>4)*4+reg
  const int cb = ntile * 128 + wc * 64;
  const int rb = mtile * 128 + wr * 64;
#pragma unroll
  for (int fr = 0; fr < 4; ++fr) {
#pragma unroll
    for (int j = 0; j < 4; ++j) {
      float v0 = acc[fr][0][j] + bv[0];
      float v1 = acc[fr][1][j] + bv[1];
      float v2 = acc[fr][2][j] + bv[2];
      float v3 = acc[fr][3][j] + bv[3];
      if (EPI == 0) {
        float mx = fmaxf(fmaxf(v0, v1), fmaxf(v2, v3));
#pragma unroll
        for (int mk = 1; mk < 16; mk <<= 1) mx = fmaxf(mx, __shfl_xor(mx, mk, 64));
        v0 = __expf(v0 - mx); v1 = __expf(v1 - mx);
        v2 = __expf(v2 - mx); v3 = __expf(v3 - mx);
        float s = v0 + v1 + v2 + v3;
#pragma unroll
        for (int mk = 1; mk < 16; mk <<= 1) s += __shfl_xor(s, mk, 64);
        const float inv = 1.f / s;
        v0 *= inv; v1 *= inv; v2 *= inv; v3 *= inv;
      }
      const size_t row = (size_t)(rb + fr * 16 + lg * 4 + j);
      if (EPI == 2) {
        float* o = (float*)outp;
        o[row * EDIM + cb +  0 + lr] = v0;
        o[row * EDIM + cb + 16 + lr] = v1;
        o[row * EDIM + cb + 32 + lr] = v2;
        o[row * EDIM + cb + 48 + lr] = v3;
      } else {
        unsigned short* o = (unsigned short*)outp;
        o[row * EDIM + cb +  0 + lr] = f2bf(v0);
        o[row * EDIM + cb + 16 + lr] = f2bf(v1);
        o[row * EDIM + cb + 32 + lr] = f2bf(v2);
        o[row * EDIM + cb + 48 + lr] = f2bf(v3);
      }
    }
  }
}

// ---------------- kvT[e][d] = sum_l v[l,e]*k[l,d] (64x64 per b,h) + ksum ----------------
__global__ __launch_bounds__(256) void reduce_kvT_k(
    const unsigned short* __restrict__ Kb, const unsigned short* __restrict__ Vb,
    float* __restrict__ KVT, float* __restrict__ KS) {
  __shared__ unsigned short sK[64][80];
  __shared__ unsigned short sV[64][80];
  const int t = threadIdx.x;
  const int bh = blockIdx.y;
  const int b = bh >> 3, h = bh & 7;
  const int ty = t >> 4, tx = t & 15;
  const int srow = t >> 2, scol = (t & 3) * 16;
  const size_t base = ((size_t)b * LSEQ + (size_t)blockIdx.x * 512) * EDIM + h * 64;
  float acc[4][4];
#pragma unroll
  for (int i = 0; i < 4; ++i)
#pragma unroll
    for (int j = 0; j < 4; ++j) acc[i][j] = 0.f;
  float ks[4] = {0.f, 0.f, 0.f, 0.f};

  for (int sub = 0; sub < 8; ++sub) {
    const size_t g = base + (size_t)(sub * 64 + srow) * EDIM + scol;
    *(uint4*)&sK[srow][scol]     = *(const uint4*)(Kb + g);
    *(uint4*)&sK[srow][scol + 8] = *(const uint4*)(Kb + g + 8);
    *(uint4*)&sV[srow][scol]     = *(const uint4*)(Vb + g);
    *(uint4*)&sV[srow][scol + 8] = *(const uint4*)(Vb + g + 8);
    __syncthreads();
#pragma unroll 4
    for (int l = 0; l < 64; ++l) {
      const ushort4 ku = *(const ushort4*)&sK[l][ty * 4];
      const ushort4 vu = *(const ushort4*)&sV[l][tx * 4];
      const float kf[4] = {bf2f(ku.x), bf2f(ku.y), bf2f(ku.z), bf2f(ku.w)};
      const float vf[4] = {bf2f(vu.x), bf2f(vu.y), bf2f(vu.z), bf2f(vu.w)};
#pragma unroll
      for (int i = 0; i < 4; ++i)
#pragma unroll
        for (int j = 0; j < 4; ++j) acc[i][j] = fmaf(kf[i], vf[j], acc[i][j]);
      if (tx == 0) {
#pragma unroll
        for (int i = 0; i < 4; ++i) ks[i] += kf[i];
      }
    }
    __syncthreads();
  }
  float* kvd = KVT + (size_t)bh * 4096;  // [e][d]
#pragma unroll
  for (int i = 0; i < 4; ++i)
#pragma unroll
    for (int j = 0; j < 4; ++j)
      atomicAdd(&kvd[(tx * 4 + j) * 64 + (ty * 4 + i)], acc[i][j]);
  if (tx == 0) {
#pragma unroll
    for (int i = 0; i < 4; ++i) atomicAdd(&KS[bh * 64 + ty * 4 + i], ks[i]);
  }
}

// ---------------- combine: Res = q + 0.5*(a0*q@kv0 + a1*q@kv1), MFMA ----------------
// block: 256 rows x 1 head; q tile in LDS (XOR-swizzled via pre-swizzled glds source).
__global__ __launch_bounds__(256) void combine2_k(
    const unsigned short* __restrict__ Qb,
    const float* __restrict__ KVT0, const float* __restrict__ KVT1,
    const float* __restrict__ KS0, const float* __restrict__ KS1,
    unsigned short* __restrict__ Res) {
  __shared__ unsigned short sQ[256 * 64];  // swizzled: chunk c holds src chunk c^(row&7)
  __shared__ float sAl[2][256];
  __shared__ float sKs[2][64];
  const int t = threadIdx.x;
  const int bh = blockIdx.y, b = bh >> 3, h = bh & 7;
  const int l0 = blockIdx.x * 256;
  const int w = t >> 6, lane = t & 63, lg = lane >> 4, lr = lane & 15;
  const size_t qbase = ((size_t)b * LSEQ + l0) * EDIM + h * 64;

#pragma unroll
  for (int i = 0; i < 8; ++i) {
    const int chunk = i * 256 + t;          // 16B units
    const int row = chunk >> 3;
    const int sc = chunk ^ (row & 7);       // inverse-swizzled source chunk (same row)
    const int col = (sc & 7) * 8;
    glds16(Qb + qbase + (size_t)row * EDIM + col, sQ + (size_t)chunk * 8);
  }
  if (t < 64) { sKs[0][t] = KS0[bh * 64 + t]; sKs[1][t] = KS1[bh * 64 + t]; }
  __syncthreads();

  // alpha: thread t = row t
  {
    const int row = t;
    float d0 = 0.f, d1 = 0.f;
#pragma unroll
    for (int c = 0; c < 8; ++c) {
      const int m = c ^ (row & 7);
      const bf16x8 qv = *(const bf16x8*)&sQ[(row * 8 + m) * 8];
#pragma unroll
      for (int u = 0; u < 8; ++u) {
        const float qf = (float)qv[u];
        d0 = fmaf(qf, sKs[0][c * 8 + u], d0);
        d1 = fmaf(qf, sKs[1][c * 8 + u], d1);
      }
    }
    sAl[0][row] = 1.f / d0;
    sAl[1][row] = 1.f / d1;
  }
  __syncthreads();

  f32x4 a0[4][4], a1[4][4];
#pragma unroll
  for (int i = 0; i < 4; ++i)
#pragma unroll
    for (int j = 0; j < 4; ++j)
#pragma unroll
      for (int c = 0; c < 4; ++c) { a0[i][j][c] = 0.f; a1[i][j][c] = 0.f; }

  const float* kvt0 = KVT0 + (size_t)bh * 4096;
  const float* kvt1 = KVT1 + (size_t)bh * 4096;
#pragma unroll
  for (int fn = 0; fn < 2; ++fn) {
    const float* kvt = fn ? kvt1 : kvt0;
    f32x4 (*acc)[4] = fn ? a1 : a0;
#pragma unroll
    for (int kh = 0; kh < 2; ++kh) {
      const int kk = kh * 32;
      bf16x8 bfr[4];
#pragma unroll
      for (int fc = 0; fc < 4; ++fc) {
        const float* sp = kvt + (fc * 16 + lr) * 64 + kk + lg * 8;
        const float4 x = *(const float4*)sp;
        const float4 y = *(const float4*)(sp + 4);
        bf16x8 bb;
        bb[0] = (__bf16)x.x; bb[1] = (__bf16)x.y; bb[2] = (__bf16)x.z; bb[3] = (__bf16)x.w;
        bb[4] = (__bf16)y.x; bb[5] = (__bf16)y.y; bb[6] = (__bf16)y.z; bb[7] = (__bf16)y.w;
        bfr[fc] = bb;
      }
      bf16x8 af[4];
#pragma unroll
      for (int fr = 0; fr < 4; ++fr) {
        const int row = w * 64 + fr * 16 + lr;
        const int m = (kh * 4 + lg) ^ (row & 7);
        af[fr] = *(const bf16x8*)&sQ[(row * 8 + m) * 8];
      }
#pragma unroll
      for (int fr = 0; fr < 4; ++fr)
#pragma unroll
        for (int fc = 0; fc < 4; ++fc)
          acc[fr][fc] = __builtin_amdgcn_mfma_f32_16x16x32_bf16(af[fr], bfr[fc], acc[fr][fc], 0, 0, 0);
    }
  }

  const size_t obase = ((size_t)b * LSEQ + l0) * EDIM + h * 64;
#pragma unroll
  for (int fr = 0; fr < 4; ++fr) {
#pragma unroll
    for (int j = 0; j < 4; ++j) {
      const int row = w * 64 + fr * 16 + lg * 4 + j;
      const float al0 = 0.5f * sAl[0][row];
      const float al1 = 0.5f * sAl[1][row];
      const size_t rb = obase + (size_t)row * EDIM;
#pragma unroll
      for (int fc = 0; fc < 4; ++fc) {
        const int col = fc * 16 + lr;
        const int m = (col >> 3) ^ (row & 7);
        const float qf = bf2f(sQ[(row * 8 + m) * 8 + (col & 7)]);
        const float r = qf + al0 * a0[fr][fc][j] + al1 * a1[fr][fc][j];
        Res[rb + col] = f2bf(r);
      }
    }
  }
}

extern "C" void kernel_launch(void* const* d_in, const int* in_sizes, int n_in,
                              void* d_out, int out_size, void* d_ws, size_t ws_size,
                              hipStream_t stream) {
  const float* query = (const float*)d_in[0];
  const float* f0    = (const float*)d_in[1];
  const float* f1    = (const float*)d_in[2];
  const float* Wq  = (const float*)d_in[3];  const float* bq  = (const float*)d_in[4];
  const float* Wk0 = (const float*)d_in[5];  const float* bk0 = (const float*)d_in[6];
  const float* Wv0 = (const float*)d_in[7];  const float* bv0 = (const float*)d_in[8];
  const float* Wk1 = (const float*)d_in[9];  const float* bk1 = (const float*)d_in[10];
  const float* Wv1 = (const float*)d_in[11]; const float* bv1 = (const float*)d_in[12];
  const float* Wo  = (const float*)d_in[13]; const float* bo  = (const float*)d_in[14];
  char* ws = (char*)d_ws;

  // ws: [0,3M) bf16 weights; [4M,5M+16K) kvT0,kvT1,ks0,ks1 (zeroed);
  // [8M,40M) Qb; [40M,72M) Kb (reused as Res); [72M,104M) Vb (first reused as query-bf16).
  // d_out (64MB f32) doubles as the f0/f1 bf16 staging buffer until the final GEMM.
  unsigned short* WB  = (unsigned short*)ws;
  float* KVT0 = (float*)(ws + (4ull << 20));
  float* KVT1 = (float*)(ws + (4ull << 20) + (512ull << 10));
  float* KS0  = (float*)(ws + (5ull << 20));
  float* KS1  = (float*)(ws + (5ull << 20) + (8ull << 10));
  unsigned short* Qb = (unsigned short*)(ws + (8ull << 20));
  unsigned short* Kb = (unsigned short*)(ws + (40ull << 20));
  unsigned short* Vb = (unsigned short*)(ws + (72ull << 20));
  unsigned short* tQ = Vb;                       // query-bf16, dead before v0-GEMM writes Vb
  unsigned short* TF = (unsigned short*)d_out;   // f-bf16 staging, dead before final GEMM
  unsigned short* Resb = Kb;                     // Kb dead after reduce1
  float* outp = (float*)d_out;

  hipMemsetAsync(ws + (4ull << 20), 0, (1ull << 20) + (16ull << 10), stream);
  cast_w_k<<<dim3(128, 6), dim3(256), 0, stream>>>(Wq, Wk0, Wv0, Wk1, Wv1, Wo, WB);
  cast_in_k<<<dim3(8192), dim3(256), 0, stream>>>(query, tQ);
  cast_in_k<<<dim3(8192), dim3(256), 0, stream>>>(f0, TF);

  const dim3 gg(256, 4), gb(256);
  gemm2_k<0><<<gg, gb, 0, stream>>>(tQ, WB + 0 * 262144, bq, Qb);    // q softmax
  gemm2_k<0><<<gg, gb, 0, stream>>>(TF, WB + 1 * 262144, bk0, Kb);   // k0 softmax
  gemm2_k<1><<<gg, gb, 0, stream>>>(TF, WB + 2 * 262144, bv0, Vb);   // v0 (kills tQ)
  reduce_kvT_k<<<dim3(16, 32), gb, 0, stream>>>(Kb, Vb, KVT0, KS0);
  cast_in_k<<<dim3(8192), dim3(256), 0, stream>>>(f1, TF);
  gemm2_k<0><<<gg, gb, 0, stream>>>(TF, WB + 3 * 262144, bk1, Kb);   // k1
  gemm2_k<1><<<gg, gb, 0, stream>>>(TF, WB + 4 * 262144, bv1, Vb);   // v1
  reduce_kvT_k<<<dim3(16, 32), gb, 0, stream>>>(Kb, Vb, KVT1, KS1);
  combine2_k<<<dim3(32, 32), gb, 0, stream>>>(Qb, KVT0, KVT1, KS0, KS1, Resb);
  gemm2_k<2><<<gg, gb, 0, stream>>>(Resb, WB + 5 * 262144, bo, outp);  // final

  (void)in_sizes; (void)n_in; (void)out_size; (void)ws_size;
}

// Round 3
// 479.722 us; speedup vs baseline: 1.5080x; 1.2726x over previous
//
#include <hip/hip_runtime.h>

// LinearAttention B=4 L=8192 E=512 H=8 D=64.
// R3: fused k-GEMM + v-GEMM + MFMA kv-reduce (transposed XOR-swizzled LDS),
// partials + reduce2 (no atomic contention). q-GEMM and final GEMM unchanged.

#define DEVI __device__ __forceinline__

using bf16x8 = __attribute__((ext_vector_type(8))) __bf16;
using f32x4  = __attribute__((ext_vector_type(4))) float;

static constexpr int LSEQ = 8192;
static constexpr int EDIM = 512;

DEVI unsigned short f2bf(float f) {  // RNE f32->bf16
  unsigned int u = __builtin_bit_cast(unsigned int, f);
  u += 0x7FFFu + ((u >> 16) & 1u);
  return (unsigned short)(u >> 16);
}
DEVI float bf2f(unsigned short s) {
  unsigned int u = ((unsigned int)s) << 16;
  return __builtin_bit_cast(float, u);
}

DEVI void glds16(const void* g, void* l) {
  __builtin_amdgcn_global_load_lds(
      (const __attribute__((address_space(1))) void*)g,
      (__attribute__((address_space(3))) void*)l, 16, 0, 0);
}

// element index into a [128][128] bf16 LDS tile, chunk-XOR swizzled (T2):
// 16B chunk (row>>3) XORed with (col&7) -> conflict-free-ish col reads.
DEVI int swz(int col, int row) {
  return col * 128 + ((((row >> 3) ^ (col & 7)) << 3) | (row & 7));
}

// ---------------- weight cast: 6 x [512x512] f32 -> bf16 ----------------
__global__ __launch_bounds__(256) void cast_w_k(
    const float* __restrict__ W0, const float* __restrict__ W1,
    const float* __restrict__ W2, const float* __restrict__ W3,
    const float* __restrict__ W4, const float* __restrict__ W5,
    unsigned short* __restrict__ dst) {
  const int m = blockIdx.y;
  const float* src = (m == 0) ? W0 : (m == 1) ? W1 : (m == 2) ? W2
                   : (m == 3) ? W3 : (m == 4) ? W4 : W5;
  const int idx = (blockIdx.x * 256 + threadIdx.x) * 8;
  const float4 a = *(const float4*)(src + idx);
  const float4 b = *(const float4*)(src + idx + 4);
  union { unsigned short u[8]; uint4 v; } p;
  p.u[0] = f2bf(a.x); p.u[1] = f2bf(a.y); p.u[2] = f2bf(a.z); p.u[3] = f2bf(a.w);
  p.u[4] = f2bf(b.x); p.u[5] = f2bf(b.y); p.u[6] = f2bf(b.z); p.u[7] = f2bf(b.w);
  *(uint4*)(dst + (size_t)m * 262144 + idx) = p.v;
}

// ---------------- input cast: [32768x512] f32 -> bf16 ----------------
__global__ __launch_bounds__(256) void cast_in_k(
    const float* __restrict__ src, unsigned short* __restrict__ dst) {
  const size_t idx = ((size_t)blockIdx.x * 256 + threadIdx.x) * 8;
  const float4 a = *(const float4*)(src + idx);
  const float4 b = *(const float4*)(src + idx + 4);
  union { unsigned short u[8]; uint4 v; } p;
  p.u[0] = f2bf(a.x); p.u[1] = f2bf(a.y); p.u[2] = f2bf(a.z); p.u[3] = f2bf(a.w);
  p.u[4] = f2bf(b.x); p.u[5] = f2bf(b.y); p.u[6] = f2bf(b.z); p.u[7] = f2bf(b.w);
  *(uint4*)(dst + idx) = p.v;
}

// ---------------- GEMM: C[M,512] = A[M,512](bf16) @ W[512,512]^T + bias ----------------
// EPI: 0 = per-head softmax -> bf16; 2 = bias -> f32
template <int EPI>
__global__ __launch_bounds__(256) void gemm2_k(
    const unsigned short* __restrict__ Ab, const unsigned short* __restrict__ Wb,
    const float* __restrict__ bias, void* __restrict__ outp) {
  __shared__ unsigned short sA[4096];
  __shared__ unsigned short sB[4096];
  const int t = threadIdx.x;
  const int mtile = blockIdx.x, ntile = blockIdx.y;
  const int w = t >> 6, lane = t & 63, lg = lane >> 4, lr = lane & 15;
  const int wr = w >> 1, wc = w & 1;
  const int srow = t >> 2, scol = (t & 3) * 8;
  const unsigned short* gA = Ab + (size_t)(mtile * 128 + srow) * EDIM + scol;
  const unsigned short* gB = Wb + (size_t)(ntile * 128 + srow) * EDIM + scol;
  unsigned short* lA = sA + t * 8;
  unsigned short* lB = sB + t * 8;

  f32x4 acc[4][4];
#pragma unroll
  for (int i = 0; i < 4; ++i)
#pragma unroll
    for (int j = 0; j < 4; ++j)
#pragma unroll
      for (int c = 0; c < 4; ++c) acc[i][j][c] = 0.f;

  float bv[4];
#pragma unroll
  for (int fc = 0; fc < 4; ++fc) bv[fc] = bias[ntile * 128 + wc * 64 + fc * 16 + lr];

  for (int kt = 0; kt < 16; ++kt) {
    const int kk = kt * 32;
    glds16(gA + kk, lA);
    glds16(gA + 64 * EDIM + kk, lA + 2048);
    glds16(gB + kk, lB);
    glds16(gB + 64 * EDIM + kk, lB + 2048);
    __syncthreads();
    bf16x8 af[4], bfr[4];
#pragma unroll
    for (int fr = 0; fr < 4; ++fr)
      af[fr] = *(const bf16x8*)&sA[(wr * 64 + fr * 16 + lr) * 32 + lg * 8];
#pragma unroll
    for (int fc = 0; fc < 4; ++fc)
      bfr[fc] = *(const bf16x8*)&sB[(wc * 64 + fc * 16 + lr) * 32 + lg * 8];
#pragma unroll
    for (int fr = 0; fr < 4; ++fr)
#pragma unroll
      for (int fc = 0; fc < 4; ++fc)
        acc[fr][fc] = __builtin_amdgcn_mfma_f32_16x16x32_bf16(af[fr], bfr[fc], acc[fr][fc], 0, 0, 0);
    __syncthreads();
  }

  const int cb = ntile * 128 + wc * 64;
  const int rb = mtile * 128 + wr * 64;
#pragma unroll
  for (int fr = 0; fr < 4; ++fr) {
#pragma unroll
    for (int j = 0; j < 4; ++j) {
      float v0 = acc[fr][0][j] + bv[0];
      float v1 = acc[fr][1][j] + bv[1];
      float v2 = acc[fr][2][j] + bv[2];
      float v3 = acc[fr][3][j] + bv[3];
      if (EPI == 0) {
        float mx = fmaxf(fmaxf(v0, v1), fmaxf(v2, v3));
#pragma unroll
        for (int mk = 1; mk < 16; mk <<= 1) mx = fmaxf(mx, __shfl_xor(mx, mk, 64));
        v0 = __expf(v0 - mx); v1 = __expf(v1 - mx);
        v2 = __expf(v2 - mx); v3 = __expf(v3 - mx);
        float s = v0 + v1 + v2 + v3;
#pragma unroll
        for (int mk = 1; mk < 16; mk <<= 1) s += __shfl_xor(s, mk, 64);
        const float inv = 1.f / s;
        v0 *= inv; v1 *= inv; v2 *= inv; v3 *= inv;
      }
      const size_t row = (size_t)(rb + fr * 16 + lg * 4 + j);
      if (EPI == 2) {
        float* o = (float*)outp;
        o[row * EDIM + cb +  0 + lr] = v0;
        o[row * EDIM + cb + 16 + lr] = v1;
        o[row * EDIM + cb + 32 + lr] = v2;
        o[row * EDIM + cb + 48 + lr] = v3;
      } else {
        unsigned short* o = (unsigned short*)outp;
        o[row * EDIM + cb +  0 + lr] = f2bf(v0);
        o[row * EDIM + cb + 16 + lr] = f2bf(v1);
        o[row * EDIM + cb + 32 + lr] = f2bf(v2);
        o[row * EDIM + cb + 48 + lr] = f2bf(v3);
      }
    }
  }
}

// ---------------- fused: k=softmax(f@Wk^T+bk), v=f@Wv^T+bv, kvT += v^T k, ksum ----------------
// grid (128 mt, 4 nt); 2 chunks of 128 rows per block; 256 threads, 4 waves.
// KVpart[((mt*4+nt)*2+h2)*4096 + e*64 + d]; KS atomics.
__global__ __launch_bounds__(256, 2) void fused_kv_k(
    const unsigned short* __restrict__ Ab,
    const unsigned short* __restrict__ Wkb, const unsigned short* __restrict__ Wvb,
    const float* __restrict__ bk, const float* __restrict__ bv,
    float* __restrict__ KVpart, float* __restrict__ KS) {
  __shared__ unsigned short sKt[128 * 128];
  __shared__ unsigned short sVt[128 * 128];
  unsigned short* sA  = sKt;           // staging aliases (disjoint lifetimes)
  unsigned short* sBk = sKt + 4096;
  unsigned short* sBv = sKt + 8192;
  const int t = threadIdx.x;
  const int mt = blockIdx.x, nt = blockIdx.y;
  const int w = t >> 6, lane = t & 63, lg = lane >> 4, lr = lane & 15;
  const int wr = w >> 1, wc = w & 1;
  const int h2 = w & 1, eh = (w >> 1) * 32;
  const int srow = t >> 2, scol = (t & 3) * 8;
  const unsigned short* gBk = Wkb + (size_t)(nt * 128 + srow) * EDIM + scol;
  const unsigned short* gBv = Wvb + (size_t)(nt * 128 + srow) * EDIM + scol;

  float bkv[4], bvv[4];
#pragma unroll
  for (int fc = 0; fc < 4; ++fc) {
    bkv[fc] = bk[nt * 128 + wc * 64 + fc * 16 + lr];
    bvv[fc] = bv[nt * 128 + wc * 64 + fc * 16 + lr];
  }

  f32x4 acc_kv[2][4];
#pragma unroll
  for (int i = 0; i < 2; ++i)
#pragma unroll
    for (int j = 0; j < 4; ++j)
#pragma unroll
      for (int c = 0; c < 4; ++c) acc_kv[i][j][c] = 0.f;
  float ksub[4] = {0.f, 0.f, 0.f, 0.f};

  for (int c = 0; c < 2; ++c) {
    const int rowbase = (mt * 2 + c) * 128;
    const unsigned short* gA = Ab + (size_t)(rowbase + srow) * EDIM + scol;
    f32x4 ak[4][4], av[4][4];
#pragma unroll
    for (int i = 0; i < 4; ++i)
#pragma unroll
      for (int j = 0; j < 4; ++j)
#pragma unroll
        for (int q = 0; q < 4; ++q) { ak[i][j][q] = 0.f; av[i][j][q] = 0.f; }

    for (int kt = 0; kt < 16; ++kt) {
      const int kk = kt * 32;
      glds16(gA + kk, sA + t * 8);
      glds16(gA + 64 * EDIM + kk, sA + 2048 + t * 8);
      glds16(gBk + kk, sBk + t * 8);
      glds16(gBk + 64 * EDIM + kk, sBk + 2048 + t * 8);
      glds16(gBv + kk, sBv + t * 8);
      glds16(gBv + 64 * EDIM + kk, sBv + 2048 + t * 8);
      __syncthreads();
      bf16x8 af[4], b8k[4], b8v[4];
#pragma unroll
      for (int fr = 0; fr < 4; ++fr)
        af[fr] = *(const bf16x8*)&sA[(wr * 64 + fr * 16 + lr) * 32 + lg * 8];
#pragma unroll
      for (int fc = 0; fc < 4; ++fc) {
        b8k[fc] = *(const bf16x8*)&sBk[(wc * 64 + fc * 16 + lr) * 32 + lg * 8];
        b8v[fc] = *(const bf16x8*)&sBv[(wc * 64 + fc * 16 + lr) * 32 + lg * 8];
      }
#pragma unroll
      for (int fr = 0; fr < 4; ++fr)
#pragma unroll
        for (int fc = 0; fc < 4; ++fc) {
          ak[fr][fc] = __builtin_amdgcn_mfma_f32_16x16x32_bf16(af[fr], b8k[fc], ak[fr][fc], 0, 0, 0);
          av[fr][fc] = __builtin_amdgcn_mfma_f32_16x16x32_bf16(af[fr], b8v[fc], av[fr][fc], 0, 0, 0);
        }
      __syncthreads();
    }

    // epilogue: softmax(ak)+bias -> sKt (transposed, swizzled); av+bias -> sVt
#pragma unroll
    for (int fr = 0; fr < 4; ++fr) {
      float tk[4][4];
#pragma unroll
      for (int j = 0; j < 4; ++j) {
        float v0 = ak[fr][0][j] + bkv[0];
        float v1 = ak[fr][1][j] + bkv[1];
        float v2 = ak[fr][2][j] + bkv[2];
        float v3 = ak[fr][3][j] + bkv[3];
        float mx = fmaxf(fmaxf(v0, v1), fmaxf(v2, v3));
#pragma unroll
        for (int mk = 1; mk < 16; mk <<= 1) mx = fmaxf(mx, __shfl_xor(mx, mk, 64));
        v0 = __expf(v0 - mx); v1 = __expf(v1 - mx);
        v2 = __expf(v2 - mx); v3 = __expf(v3 - mx);
        float s = v0 + v1 + v2 + v3;
#pragma unroll
        for (int mk = 1; mk < 16; mk <<= 1) s += __shfl_xor(s, mk, 64);
        const float inv = 1.f / s;
        v0 *= inv; v1 *= inv; v2 *= inv; v3 *= inv;
        tk[0][j] = v0; tk[1][j] = v1; tk[2][j] = v2; tk[3][j] = v3;
        ksub[0] += v0; ksub[1] += v1; ksub[2] += v2; ksub[3] += v3;
      }
      const int row0 = wr * 64 + fr * 16 + lg * 4;
#pragma unroll
      for (int fc = 0; fc < 4; ++fc) {
        const int col = wc * 64 + fc * 16 + lr;
        ushort4 pk, pv;
        pk.x = f2bf(tk[fc][0]); pk.y = f2bf(tk[fc][1]);
        pk.z = f2bf(tk[fc][2]); pk.w = f2bf(tk[fc][3]);
        pv.x = f2bf(av[fr][fc][0] + bvv[fc]); pv.y = f2bf(av[fr][fc][1] + bvv[fc]);
        pv.z = f2bf(av[fr][fc][2] + bvv[fc]); pv.w = f2bf(av[fr][fc][3] + bvv[fc]);
        *(ushort4*)&sKt[swz(col, row0)] = pk;
        *(ushort4*)&sVt[swz(col, row0)] = pv;
      }
    }
    __syncthreads();

    // kv MFMA: KVT_part[e][d] += sum over 128 rows; wave -> (h2, e-half eh)
#pragma unroll
    for (int kk = 0; kk < 128; kk += 32) {
      bf16x8 a2[2], b2[4];
#pragma unroll
      for (int f2 = 0; f2 < 2; ++f2)
        a2[f2] = *(const bf16x8*)&sVt[swz(h2 * 64 + eh + f2 * 16 + lr, kk + lg * 8)];
#pragma unroll
      for (int f3 = 0; f3 < 4; ++f3)
        b2[f3] = *(const bf16x8*)&sKt[swz(h2 * 64 + f3 * 16 + lr, kk + lg * 8)];
#pragma unroll
      for (int f2 = 0; f2 < 2; ++f2)
#pragma unroll
        for (int f3 = 0; f3 < 4; ++f3)
          acc_kv[f2][f3] = __builtin_amdgcn_mfma_f32_16x16x32_bf16(a2[f2], b2[f3], acc_kv[f2][f3], 0, 0, 0);
    }
    __syncthreads();
  }

  // partial write (no atomics)
  float* kp = KVpart + ((size_t)(mt * 4 + nt) * 2 + h2) * 4096;
#pragma unroll
  for (int f2 = 0; f2 < 2; ++f2)
#pragma unroll
    for (int f3 = 0; f3 < 4; ++f3)
#pragma unroll
      for (int j = 0; j < 4; ++j)
        kp[(eh + f2 * 16 + lg * 4 + j) * 64 + f3 * 16 + lr] = acc_kv[f2][f3][j];

  // ksum: reduce over lg groups, atomicAdd by head column
  const int b = mt >> 5;
  const int bh = b * 8 + nt * 2 + wc;
#pragma unroll
  for (int fc = 0; fc < 4; ++fc) {
    float s = ksub[fc];
    s += __shfl_xor(s, 16, 64);
    s += __shfl_xor(s, 32, 64);
    if (lg == 0) atomicAdd(&KS[bh * 64 + fc * 16 + lr], s);
  }
}

// ---------------- reduce2: KVT[bh][4096] = sum over 32 mtiles of KVpart ----------------
__global__ __launch_bounds__(256) void reduce2_k(
    const float* __restrict__ KVpart, float* __restrict__ KVT) {
  const int bh = blockIdx.x;
  const int b = bh >> 3, h = bh & 7, nt = h >> 1, h2 = h & 1;
  const int i = blockIdx.y * 256 + threadIdx.x;
  float s = 0.f;
#pragma unroll 8
  for (int m = 0; m < 32; ++m)
    s += KVpart[((size_t)((b * 32 + m) * 4 + nt) * 2 + h2) * 4096 + i];
  KVT[(size_t)bh * 4096 + i] = s;
}

// ---------------- combine: Res = q + 0.5*(a0*q@kv0 + a1*q@kv1), MFMA ----------------
__global__ __launch_bounds__(256) void combine2_k(
    const unsigned short* __restrict__ Qb,
    const float* __restrict__ KVT0, const float* __restrict__ KVT1,
    const float* __restrict__ KS0, const float* __restrict__ KS1,
    unsigned short* __restrict__ Res) {
  __shared__ unsigned short sQ[256 * 64];
  __shared__ float sAl[2][256];
  __shared__ float sKs[2][64];
  const int t = threadIdx.x;
  const int bh = blockIdx.y, b = bh >> 3, h = bh & 7;
  const int l0 = blockIdx.x * 256;
  const int w = t >> 6, lane = t & 63, lg = lane >> 4, lr = lane & 15;
  const size_t qbase = ((size_t)b * LSEQ + l0) * EDIM + h * 64;

#pragma unroll
  for (int i = 0; i < 8; ++i) {
    const int chunk = i * 256 + t;
    const int row = chunk >> 3;
    const int sc = chunk ^ (row & 7);
    const int col = (sc & 7) * 8;
    glds16(Qb + qbase + (size_t)row * EDIM + col, sQ + (size_t)chunk * 8);
  }
  if (t < 64) { sKs[0][t] = KS0[bh * 64 + t]; sKs[1][t] = KS1[bh * 64 + t]; }
  __syncthreads();

  {
    const int row = t;
    float d0 = 0.f, d1 = 0.f;
#pragma unroll
    for (int c = 0; c < 8; ++c) {
      const int m = c ^ (row & 7);
      const bf16x8 qv = *(const bf16x8*)&sQ[(row * 8 + m) * 8];
#pragma unroll
      for (int u = 0; u < 8; ++u) {
        const float qf = (float)qv[u];
        d0 = fmaf(qf, sKs[0][c * 8 + u], d0);
        d1 = fmaf(qf, sKs[1][c * 8 + u], d1);
      }
    }
    sAl[0][row] = 1.f / d0;
    sAl[1][row] = 1.f / d1;
  }
  __syncthreads();

  f32x4 a0[4][4], a1[4][4];
#pragma unroll
  for (int i = 0; i < 4; ++i)
#pragma unroll
    for (int j = 0; j < 4; ++j)
#pragma unroll
      for (int c = 0; c < 4; ++c) { a0[i][j][c] = 0.f; a1[i][j][c] = 0.f; }

  const float* kvt0 = KVT0 + (size_t)bh * 4096;
  const float* kvt1 = KVT1 + (size_t)bh * 4096;
#pragma unroll
  for (int fn = 0; fn < 2; ++fn) {
    const float* kvt = fn ? kvt1 : kvt0;
    f32x4 (*acc)[4] = fn ? a1 : a0;
#pragma unroll
    for (int kh = 0; kh < 2; ++kh) {
      const int kk = kh * 32;
      bf16x8 bfr[4];
#pragma unroll
      for (int fc = 0; fc < 4; ++fc) {
        const float* sp = kvt + (fc * 16 + lr) * 64 + kk + lg * 8;
        const float4 x = *(const float4*)sp;
        const float4 y = *(const float4*)(sp + 4);
        bf16x8 bb;
        bb[0] = (__bf16)x.x; bb[1] = (__bf16)x.y; bb[2] = (__bf16)x.z; bb[3] = (__bf16)x.w;
        bb[4] = (__bf16)y.x; bb[5] = (__bf16)y.y; bb[6] = (__bf16)y.z; bb[7] = (__bf16)y.w;
        bfr[fc] = bb;
      }
      bf16x8 af[4];
#pragma unroll
      for (int fr = 0; fr < 4; ++fr) {
        const int row = w * 64 + fr * 16 + lr;
        const int m = (kh * 4 + lg) ^ (row & 7);
        af[fr] = *(const bf16x8*)&sQ[(row * 8 + m) * 8];
      }
#pragma unroll
      for (int fr = 0; fr < 4; ++fr)
#pragma unroll
        for (int fc = 0; fc < 4; ++fc)
          acc[fr][fc] = __builtin_amdgcn_mfma_f32_16x16x32_bf16(af[fr], bfr[fc], acc[fr][fc], 0, 0, 0);
    }
  }

  const size_t obase = ((size_t)b * LSEQ + l0) * EDIM + h * 64;
#pragma unroll
  for (int fr = 0; fr < 4; ++fr) {
#pragma unroll
    for (int j = 0; j < 4; ++j) {
      const int row = w * 64 + fr * 16 + lg * 4 + j;
      const float al0 = 0.5f * sAl[0][row];
      const float al1 = 0.5f * sAl[1][row];
      const size_t rb = obase + (size_t)row * EDIM;
#pragma unroll
      for (int fc = 0; fc < 4; ++fc) {
        const int col = fc * 16 + lr;
        const int m = (col >> 3) ^ (row & 7);
        const float qf = bf2f(sQ[(row * 8 + m) * 8 + (col & 7)]);
        const float r = qf + al0 * a0[fr][fc][j] + al1 * a1[fr][fc][j];
        Res[rb + col] = f2bf(r);
      }
    }
  }
}

extern "C" void kernel_launch(void* const* d_in, const int* in_sizes, int n_in,
                              void* d_out, int out_size, void* d_ws, size_t ws_size,
                              hipStream_t stream) {
  const float* query = (const float*)d_in[0];
  const float* f0    = (const float*)d_in[1];
  const float* f1    = (const float*)d_in[2];
  const float* Wq  = (const float*)d_in[3];  const float* bq  = (const float*)d_in[4];
  const float* Wk0 = (const float*)d_in[5];  const float* bk0 = (const float*)d_in[6];
  const float* Wv0 = (const float*)d_in[7];  const float* bv0 = (const float*)d_in[8];
  const float* Wk1 = (const float*)d_in[9];  const float* bk1 = (const float*)d_in[10];
  const float* Wv1 = (const float*)d_in[11]; const float* bv1 = (const float*)d_in[12];
  const float* Wo  = (const float*)d_in[13]; const float* bo  = (const float*)d_in[14];
  char* ws = (char*)d_ws;

  // ws: [0,3M) WB; [4M,4.5M) KVT0; [4.5M,5M) KVT1; [5M,+8K) KS0; [+8K,+16K) KS1;
  // [8M,40M) TF1 then Qb; [40M,56M) KVpart then Resb [40M,72M); [72M,104M) tQ.
  // d_out doubles as TF0 (f0 bf16) until the final GEMM writes it.
  unsigned short* WB  = (unsigned short*)ws;
  float* KVT0 = (float*)(ws + (4ull << 20));
  float* KVT1 = (float*)(ws + (4608ull << 10));
  float* KS0  = (float*)(ws + (5ull << 20));
  float* KS1  = (float*)(ws + (5ull << 20) + (8ull << 10));
  unsigned short* Qb   = (unsigned short*)(ws + (8ull << 20));
  unsigned short* TF1  = Qb;                      // dead before q-GEMM writes Qb
  float* KVpart        = (float*)(ws + (40ull << 20));
  unsigned short* Resb = (unsigned short*)(ws + (40ull << 20));  // after reduce2 done
  unsigned short* tQ   = (unsigned short*)(ws + (72ull << 20));
  unsigned short* TF0  = (unsigned short*)d_out;
  float* outp = (float*)d_out;

  hipMemsetAsync(KS0, 0, 16ull << 10, stream);
  cast_w_k<<<dim3(128, 6), dim3(256), 0, stream>>>(Wq, Wk0, Wv0, Wk1, Wv1, Wo, WB);
  cast_in_k<<<dim3(8192), dim3(256), 0, stream>>>(query, tQ);
  cast_in_k<<<dim3(8192), dim3(256), 0, stream>>>(f0, TF0);
  cast_in_k<<<dim3(8192), dim3(256), 0, stream>>>(f1, TF1);

  const dim3 gb(256);
  fused_kv_k<<<dim3(128, 4), gb, 0, stream>>>(TF0, WB + 1 * 262144, WB + 2 * 262144,
                                              bk0, bv0, KVpart, KS0);
  reduce2_k<<<dim3(32, 16), gb, 0, stream>>>(KVpart, KVT0);
  fused_kv_k<<<dim3(128, 4), gb, 0, stream>>>(TF1, WB + 3 * 262144, WB + 4 * 262144,
                                              bk1, bv1, KVpart, KS1);
  reduce2_k<<<dim3(32, 16), gb, 0, stream>>>(KVpart, KVT1);

  gemm2_k<0><<<dim3(256, 4), gb, 0, stream>>>(tQ, WB + 0 * 262144, bq, Qb);   // q softmax (kills TF1)
  combine2_k<<<dim3(32, 32), gb, 0, stream>>>(Qb, KVT0, KVT1, KS0, KS1, Resb); // kills KVpart
  gemm2_k<2><<<dim3(256, 4), gb, 0, stream>>>(Resb, WB + 5 * 262144, bo, outp); // kills TF0

  (void)in_sizes; (void)n_in; (void)out_size; (void)ws_size;
}